// Round 4
// baseline (573.606 us; speedup 1.0000x reference)
//
#include <hip/hip_runtime.h>
#include <hip/hip_bf16.h>
#include <stdint.h>

typedef _Float16 f16x8 __attribute__((ext_vector_type(8)));
typedef float    f32x4 __attribute__((ext_vector_type(4)));

#define QMAX 7.0f
#define QSCALE_MIN 2e-16f

#define M_DIM 8192
#define N_DIM 4096
#define K_DIM 4096

#define BM 128
#define BN 128
#define BK 32

#define XH_BYTES ((size_t)M_DIM * K_DIM * 2)
#define WH_BYTES ((size_t)N_DIM * K_DIM * 2)
#define SCALE_BYTES ((size_t)N_DIM * 4)

// ---------------- kernel 1: per-row weight quantize (one block per row) ----
__global__ __launch_bounds__(256) void quant_weight_kernel(
    const float* __restrict__ w, const float* __restrict__ bias,
    _Float16* __restrict__ wh, float* __restrict__ scale_out,
    float* __restrict__ bdeq_out)
{
    const int row = blockIdx.x;
    const int t = threadIdx.x;
    const float* wr = w + (size_t)row * K_DIM;

    // each thread owns 16 contiguous elements
    float4 v[4];
#pragma unroll
    for (int i = 0; i < 4; ++i)
        v[i] = reinterpret_cast<const float4*>(wr)[t * 4 + i];

    float m = 0.f;
#pragma unroll
    for (int i = 0; i < 4; ++i) {
        m = fmaxf(m, fabsf(v[i].x));
        m = fmaxf(m, fabsf(v[i].y));
        m = fmaxf(m, fabsf(v[i].z));
        m = fmaxf(m, fabsf(v[i].w));
    }
#pragma unroll
    for (int off = 32; off; off >>= 1)
        m = fmaxf(m, __shfl_xor(m, off, 64));

    __shared__ float wmax[4];
    if ((t & 63) == 0) wmax[t >> 6] = m;
    __syncthreads();
    float am = fmaxf(fmaxf(wmax[0], wmax[1]), fmaxf(wmax[2], wmax[3]));
    float scale = fmaxf(am, QSCALE_MIN) / QMAX;

    // quantize: clip(w/scale, -7, 7) then round-half-even; ints exact in f16
    f16x8 q[2];
#pragma unroll
    for (int i = 0; i < 4; ++i) {
        float e[4] = { v[i].x, v[i].y, v[i].z, v[i].w };
#pragma unroll
        for (int j = 0; j < 4; ++j) {
            float d = e[j] / scale;
            d = fminf(QMAX, fmaxf(-QMAX, d));
            q[i >> 1][(i & 1) * 4 + j] = (_Float16)rintf(d);
        }
    }
    _Float16* __restrict__ dst = wh + (size_t)row * K_DIM + t * 16;
    *reinterpret_cast<f16x8*>(dst)     = q[0];
    *reinterpret_cast<f16x8*>(dst + 8) = q[1];

    if (t == 0) {
        scale_out[row] = scale;
        bdeq_out[row]  = rintf(bias[row] / scale) * scale;
    }
}

// ---------------- kernel 2: x f32 -> f16 ----------------------------------
__global__ __launch_bounds__(256) void convert_x_kernel(
    const float* __restrict__ x, _Float16* __restrict__ xh, size_t n8)
{
    size_t i = (size_t)blockIdx.x * blockDim.x + threadIdx.x;
    size_t stride = (size_t)gridDim.x * blockDim.x;
    for (size_t c = i; c < n8; c += stride) {
        float4 a = reinterpret_cast<const float4*>(x)[c * 2];
        float4 b = reinterpret_cast<const float4*>(x)[c * 2 + 1];
        f16x8 h;
        h[0] = (_Float16)a.x; h[1] = (_Float16)a.y;
        h[2] = (_Float16)a.z; h[3] = (_Float16)a.w;
        h[4] = (_Float16)b.x; h[5] = (_Float16)b.y;
        h[6] = (_Float16)b.z; h[7] = (_Float16)b.w;
        reinterpret_cast<f16x8*>(xh)[c] = h;
    }
}

// ---------------- kernel 3: GEMM C = A * B^T, epilogue scale+bias ---------
// A = xh [M][K] f16, B = wh [N][K] f16 (B^T layout), C f32 [M][N]
__global__ __launch_bounds__(256) void gemm_kernel(
    const _Float16* __restrict__ A, const _Float16* __restrict__ B,
    const float* __restrict__ scale, const float* __restrict__ bdeq,
    float* __restrict__ C)
{
    __shared__ _Float16 As[BM * BK];   // 8 KB
    __shared__ _Float16 Bs[BN * BK];   // 8 KB

    const int t = threadIdx.x;
    const int l = t & 63;
    const int w = t >> 6;

    // XCD-aware bijective swizzle (nwg = 2048, divisible by 8)
    const int nwg = gridDim.x;
    const int cpx = nwg >> 3;
    const int bid = blockIdx.x;
    const int swz = (bid & 7) * cpx + (bid >> 3);
    const int nbn = N_DIM / BN;                // 32
    const int bm = swz / nbn, bn = swz % nbn;

    const int wrow = w >> 1, wcol = w & 1;     // 2x2 wave grid, 64x64 each

    f32x4 acc[4][4] = {};

    // staging: issue i, thread t covers tile bytes [i*4096 + t*16)
    // element e = (i*256+t)*8 ; r = e>>5 ; c = e&31   (row-major [128][32])
    const int e0 = t * 8;
    const int r0 = e0 >> 5, c0 = e0 & 31;          // issue 0
    const int e1 = (256 + t) * 8;
    const int r1 = e1 >> 5, c1 = e1 & 31;          // issue 1

    const _Float16* gA0 = A + ((size_t)(bm * BM + r0)) * K_DIM + c0;
    const _Float16* gA1 = A + ((size_t)(bm * BM + r1)) * K_DIM + c1;
    const _Float16* gB0 = B + ((size_t)(bn * BN + r0)) * K_DIM + c0;
    const _Float16* gB1 = B + ((size_t)(bn * BN + r1)) * K_DIM + c1;

    // wave-uniform LDS destinations (thread t covers tile bytes t*16)
    char* ldsA0 = (char*)As + w * 1024;
    char* ldsA1 = (char*)As + 4096 + w * 1024;
    char* ldsB0 = (char*)Bs + w * 1024;
    char* ldsB1 = (char*)Bs + 4096 + w * 1024;

    typedef __attribute__((address_space(1))) const void gvoid;
    typedef __attribute__((address_space(3))) void lvoid;

    for (int kt = 0; kt < K_DIM; kt += BK) {
        __builtin_amdgcn_global_load_lds((gvoid*)(gA0 + kt), (lvoid*)ldsA0, 16, 0, 0);
        __builtin_amdgcn_global_load_lds((gvoid*)(gA1 + kt), (lvoid*)ldsA1, 16, 0, 0);
        __builtin_amdgcn_global_load_lds((gvoid*)(gB0 + kt), (lvoid*)ldsB0, 16, 0, 0);
        __builtin_amdgcn_global_load_lds((gvoid*)(gB1 + kt), (lvoid*)ldsB1, 16, 0, 0);
        __syncthreads();   // compiler drains vmcnt before the barrier

        f16x8 a[4], b[4];
#pragma unroll
        for (int i = 0; i < 4; ++i)
            a[i] = *reinterpret_cast<const f16x8*>(
                &As[(wrow * 64 + i * 16 + (l & 15)) * BK + (l >> 4) * 8]);
#pragma unroll
        for (int j = 0; j < 4; ++j)
            b[j] = *reinterpret_cast<const f16x8*>(
                &Bs[(wcol * 64 + j * 16 + (l & 15)) * BK + (l >> 4) * 8]);

#pragma unroll
        for (int i = 0; i < 4; ++i)
#pragma unroll
            for (int j = 0; j < 4; ++j)
                acc[i][j] = __builtin_amdgcn_mfma_f32_16x16x32_f16(
                    a[i], b[j], acc[i][j], 0, 0, 0);

        __syncthreads();   // protect LDS before next stage overwrites
    }

    // epilogue: out = acc*scale[n] + bdeq[n]
    const int rowg = bm * BM + wrow * 64;
    const int colg = bn * BN + wcol * 64;
#pragma unroll
    for (int j = 0; j < 4; ++j) {
        const int n = colg + j * 16 + (l & 15);
        const float s = scale[n];
        const float bd = bdeq[n];
#pragma unroll
        for (int i = 0; i < 4; ++i) {
            const int mbase = rowg + i * 16 + (l >> 4) * 4;
#pragma unroll
            for (int r = 0; r < 4; ++r)
                C[(size_t)(mbase + r) * N_DIM + n] = acc[i][j][r] * s + bd;
        }
    }
}

// ---------------- fallback path (only if ws_size too small) ----------------
__global__ __launch_bounds__(256) void scale_only_kernel(
    const float* __restrict__ w, const float* __restrict__ bias,
    float* __restrict__ scale_out, float* __restrict__ bdeq_out)
{
    const int row = blockIdx.x;
    const int t = threadIdx.x;
    const float* wr = w + (size_t)row * K_DIM;
    float m = 0.f;
#pragma unroll
    for (int i = 0; i < 4; ++i) {
        float4 v = reinterpret_cast<const float4*>(wr)[t * 4 + i];
        m = fmaxf(m, fmaxf(fmaxf(fabsf(v.x), fabsf(v.y)),
                           fmaxf(fabsf(v.z), fabsf(v.w))));
    }
#pragma unroll
    for (int off = 32; off; off >>= 1)
        m = fmaxf(m, __shfl_xor(m, off, 64));
    __shared__ float wmax[4];
    if ((t & 63) == 0) wmax[t >> 6] = m;
    __syncthreads();
    if (t == 0) {
        float am = fmaxf(fmaxf(wmax[0], wmax[1]), fmaxf(wmax[2], wmax[3]));
        float scale = fmaxf(am, QSCALE_MIN) / QMAX;
        scale_out[row] = scale;
        bdeq_out[row]  = rintf(bias[row] / scale) * scale;
    }
}

// naive-but-correct f32 GEMM with on-the-fly dequant, 32x32 tiles
__global__ __launch_bounds__(256) void fallback_gemm(
    const float* __restrict__ x, const float* __restrict__ w,
    const float* __restrict__ scale, const float* __restrict__ bdeq,
    float* __restrict__ C)
{
    __shared__ float xs[32][33];
    __shared__ float wt[32][33];
    const int nbn = N_DIM / 32;
    const int bn = blockIdx.x % nbn, bm = blockIdx.x / nbn;
    const int tx = threadIdx.x & 31, ty = threadIdx.x >> 5;   // ty 0..7
    float acc[4] = {0.f, 0.f, 0.f, 0.f};
    for (int kt = 0; kt < K_DIM; kt += 32) {
        __syncthreads();
#pragma unroll
        for (int i = 0; i < 4; ++i) {
            int r = ty + i * 8;
            xs[r][tx] = x[(size_t)(bm * 32 + r) * K_DIM + kt + tx];
            float s = scale[bn * 32 + r];
            float wv = w[(size_t)(bn * 32 + r) * K_DIM + kt + tx];
            wt[r][tx] = rintf(fminf(QMAX, fmaxf(-QMAX, wv / s))) * s;
        }
        __syncthreads();
#pragma unroll 8
        for (int kk = 0; kk < 32; ++kk) {
            float wv = wt[tx][kk];
#pragma unroll
            for (int i = 0; i < 4; ++i)
                acc[i] = fmaf(xs[ty + i * 8][kk], wv, acc[i]);
        }
    }
    const float bd = bdeq[bn * 32 + tx];
#pragma unroll
    for (int i = 0; i < 4; ++i)
        C[(size_t)(bm * 32 + ty + i * 8) * N_DIM + bn * 32 + tx] = acc[i] + bd;
}

extern "C" void kernel_launch(void* const* d_in, const int* in_sizes, int n_in,
                              void* d_out, int out_size, void* d_ws, size_t ws_size,
                              hipStream_t stream)
{
    const float* x    = (const float*)d_in[0];   // 4*2048*4096 f32
    const float* wgt  = (const float*)d_in[1];   // 4096*4096 f32
    const float* bias = (const float*)d_in[2];   // 4096 f32
    float* out = (float*)d_out;

    char* ws = (char*)d_ws;

    if (ws_size >= XH_BYTES + WH_BYTES + 2 * SCALE_BYTES) {
        // fast path: xh 64MB | wh 32MB | scale 16KB | bdeq 16KB
        _Float16* xh   = (_Float16*)(ws);
        _Float16* wh   = (_Float16*)(ws + XH_BYTES);
        float* scale   = (float*)(ws + XH_BYTES + WH_BYTES);
        float* bdeq    = scale + N_DIM;

        quant_weight_kernel<<<N_DIM, 256, 0, stream>>>(wgt, bias, wh, scale, bdeq);
        convert_x_kernel<<<2048, 256, 0, stream>>>(x, xh, (size_t)M_DIM * K_DIM / 8);
        gemm_kernel<<<(M_DIM / BM) * (N_DIM / BN), 256, 0, stream>>>(
            xh, wh, scale, bdeq, out);
    } else {
        // fallback: needs only 32 KB of ws
        float* scale = (float*)ws;
        float* bdeq  = scale + N_DIM;
        scale_only_kernel<<<N_DIM, 256, 0, stream>>>(wgt, bias, scale, bdeq);
        fallback_gemm<<<(M_DIM / 32) * (N_DIM / 32), 256, 0, stream>>>(
            x, wgt, scale, bdeq, out);
    }
}

// Round 5
// 515.165 us; speedup vs baseline: 1.1134x; 1.1134x over previous
//
#include <hip/hip_runtime.h>
#include <hip/hip_bf16.h>
#include <stdint.h>

typedef _Float16 f16x8 __attribute__((ext_vector_type(8)));
typedef _Float16 f16x4 __attribute__((ext_vector_type(4)));
typedef float    f32x4 __attribute__((ext_vector_type(4)));

#define QMAX 7.0f
#define QSCALE_MIN 2e-16f

#define M_DIM 8192
#define N_DIM 4096
#define K_DIM 4096

// 8-phase GEMM geometry (m201 template)
#define NT 64   // K tiles of BK=64

#define XH_BYTES ((size_t)M_DIM * K_DIM * 2)
#define WH_BYTES ((size_t)N_DIM * K_DIM * 2)
#define SCALE_BYTES ((size_t)N_DIM * 4)

typedef __attribute__((address_space(1))) const void gvoid;
typedef __attribute__((address_space(3))) void lvoid;

#define BAR()  asm volatile("s_barrier" ::: "memory")
#define LGK0() asm volatile("s_waitcnt lgkmcnt(0)" ::: "memory")

// ---------------- kernel 1: per-row weight quantize (one block per row) ----
__global__ __launch_bounds__(256) void quant_weight_kernel(
    const float* __restrict__ w, const float* __restrict__ bias,
    _Float16* __restrict__ wh, float* __restrict__ scale_out,
    float* __restrict__ bdeq_out)
{
    const int row = blockIdx.x;
    const int t = threadIdx.x;
    const float* wr = w + (size_t)row * K_DIM;

    // coalesced: pass i reads float4 index i*256 + t (stride-1 across lanes)
    float4 v[4];
#pragma unroll
    for (int i = 0; i < 4; ++i)
        v[i] = reinterpret_cast<const float4*>(wr)[i * 256 + t];

    float m = 0.f;
#pragma unroll
    for (int i = 0; i < 4; ++i) {
        m = fmaxf(m, fabsf(v[i].x));
        m = fmaxf(m, fabsf(v[i].y));
        m = fmaxf(m, fabsf(v[i].z));
        m = fmaxf(m, fabsf(v[i].w));
    }
#pragma unroll
    for (int off = 32; off; off >>= 1)
        m = fmaxf(m, __shfl_xor(m, off, 64));

    __shared__ float wmax[4];
    if ((t & 63) == 0) wmax[t >> 6] = m;
    __syncthreads();
    float am = fmaxf(fmaxf(wmax[0], wmax[1]), fmaxf(wmax[2], wmax[3]));
    float scale = fmaxf(am, QSCALE_MIN) / QMAX;

    // quantize: clip(w/scale, -7, 7) then round-half-even; ints exact in f16
#pragma unroll
    for (int i = 0; i < 4; ++i) {
        float e[4] = { v[i].x, v[i].y, v[i].z, v[i].w };
        f16x4 q;
#pragma unroll
        for (int j = 0; j < 4; ++j) {
            float d = e[j] / scale;
            d = fminf(QMAX, fmaxf(-QMAX, d));
            q[j] = (_Float16)rintf(d);
        }
        reinterpret_cast<f16x4*>(wh + (size_t)row * K_DIM)[i * 256 + t] = q;
    }

    if (t == 0) {
        scale_out[row] = scale;
        bdeq_out[row]  = rintf(bias[row] / scale) * scale;
    }
}

// ---------------- kernel 2: x f32 -> f16 ----------------------------------
__global__ __launch_bounds__(256) void convert_x_kernel(
    const float* __restrict__ x, _Float16* __restrict__ xh, size_t n8)
{
    size_t i = (size_t)blockIdx.x * blockDim.x + threadIdx.x;
    size_t stride = (size_t)gridDim.x * blockDim.x;
    for (size_t c = i; c < n8; c += stride) {
        float4 a = reinterpret_cast<const float4*>(x)[c * 2];
        float4 b = reinterpret_cast<const float4*>(x)[c * 2 + 1];
        f16x8 h;
        h[0] = (_Float16)a.x; h[1] = (_Float16)a.y;
        h[2] = (_Float16)a.z; h[3] = (_Float16)a.w;
        h[4] = (_Float16)b.x; h[5] = (_Float16)b.y;
        h[6] = (_Float16)b.z; h[7] = (_Float16)b.w;
        reinterpret_cast<f16x8*>(xh)[c] = h;
    }
}

// ---------------- kernel 3: 256x256 8-phase GEMM, C = A*B^T ---------------
// A [M][K] f16, B [N][K] f16. 512 threads = 8 waves (2M x 4N), BK=64.
// LDS 128 KiB: A region [2 dbuf][2 half][128][64] f16 at 0, B region at 65536.
// st_16x32 swizzle: storage byte b' = b ^ (((b>>9)&1)<<5), applied via
// pre-swizzled SOURCE (linear gload_lds dest) + swizzled ds_read offsets.
__global__ __launch_bounds__(512, 2) void gemm_kernel(
    const _Float16* __restrict__ A, const _Float16* __restrict__ B,
    const float* __restrict__ scale, const float* __restrict__ bdeq,
    float* __restrict__ C)
{
    __shared__ __attribute__((aligned(128))) char smem[131072];

    const int tid = threadIdx.x;
    const int l = tid & 63;
    const int w = tid >> 6;        // wave 0..7
    const int wm = w >> 2;         // 0..1  (rows wm*128..+128)
    const int wn = w & 3;          // 0..3  (cols wn*64..+64)

    // XCD bijective swizzle (512 blocks, 512%8==0)
    const int bid = blockIdx.x;
    const int swz = (bid & 7) * 64 + (bid >> 3);
    const int bm = swz >> 4;       // 0..31
    const int bn = swz & 15;       // 0..15

    // ---- read-side per-lane constants (swizzle folded into kofs) ----
    const int lrow = l & 15;
    const unsigned kofs = (unsigned)(((l >> 4) * 16) ^ ((l & 4) << 3));
    const unsigned aOff = (unsigned)(wm * 16384 + lrow * 128) + kofs;
    const unsigned bOff = 65536u +
        (unsigned)((wn >> 1) * 16384 + (wn & 1) * 8192 + lrow * 128) + kofs;

    // ---- stage-side per-lane constants (inverse swizzle on source) ----
    const int tp = tid ^ (((tid >> 5) & 1) << 1);
    const int rowq = tp >> 3;              // 0..63
    const int colE = (tp & 7) * 8;         // f16 elements
    const _Float16* aSrc = A + (size_t)(bm * 256 + rowq) * K_DIM + colE;
    const _Float16* bSrc = B + (size_t)(bn * 256 + rowq) * K_DIM + colE;
    const unsigned wOfs = (unsigned)(w * 1024);

    // half-tile issue sequence: s -> tile T=s>>2, part s&3: 0:Bh0 1:Bh1 2:Ah0 3:Ah1
    auto stage = [&](int s) {
        int T = s >> 2;
        if (T >= NT) return;
        int part = s & 3;
        int half = part & 1;
        bool isB = part < 2;
        const _Float16* src = (isB ? bSrc : aSrc)
                              + (size_t)(half * 128) * K_DIM + T * 64;
        unsigned dst = (isB ? 65536u : 0u) + (unsigned)((T & 1) * 32768)
                       + (unsigned)(half * 16384) + wOfs;
        __builtin_amdgcn_global_load_lds((gvoid*)src,
                                         (lvoid*)(smem + dst), 16, 0, 0);
        __builtin_amdgcn_global_load_lds((gvoid*)(src + (size_t)64 * K_DIM),
                                         (lvoid*)(smem + dst + 8192), 16, 0, 0);
    };

    f32x4 acc[8][4];
#pragma unroll
    for (int i = 0; i < 8; ++i)
#pragma unroll
        for (int j = 0; j < 4; ++j)
            acc[i][j] = (f32x4){0.f, 0.f, 0.f, 0.f};

    f16x8 a[4][2], b[4][2];

    // ---- prologue: tile0 complete + tile1 first 3 halves ----
    stage(0); stage(1); stage(2); stage(3);
    asm volatile("s_waitcnt vmcnt(4)" ::: "memory");
    stage(4); stage(5); stage(6);
    asm volatile("s_waitcnt vmcnt(6)" ::: "memory");
    BAR();

    for (int t = 0; t < NT; ++t) {
        const unsigned dbuf = (unsigned)((t & 1) * 32768);
        const int sb = 7 + 4 * t;

        // ---- P1: read A-low (8) + all B (8); stage (t+1).Ah1; MFMA rows0-63 x cols0-31
#pragma unroll
        for (int i = 0; i < 4; ++i)
#pragma unroll
            for (int kq = 0; kq < 2; ++kq)
                a[i][kq] = *(const f16x8*)(smem + (aOff + dbuf
                                + (unsigned)(i * 2048 + kq * 64)));
#pragma unroll
        for (int j = 0; j < 4; ++j)
#pragma unroll
            for (int kq = 0; kq < 2; ++kq)
                b[j][kq] = *(const f16x8*)(smem + (bOff + dbuf
                                + (unsigned)(j * 2048 + kq * 64)));
        stage(sb);
        BAR(); LGK0();
        __builtin_amdgcn_s_setprio(1);
#pragma unroll
        for (int i = 0; i < 4; ++i)
#pragma unroll
            for (int j = 0; j < 2; ++j)
#pragma unroll
                for (int kq = 0; kq < 2; ++kq)
                    acc[i][j] = __builtin_amdgcn_mfma_f32_16x16x32_f16(
                        a[i][kq], b[j][kq], acc[i][j], 0, 0, 0);
        __builtin_amdgcn_s_setprio(0);
        BAR();

        // ---- P2: stage (t+2).Bh0; MFMA rows0-63 x cols32-63
        stage(sb + 1);
        BAR(); LGK0();
        __builtin_amdgcn_s_setprio(1);
#pragma unroll
        for (int i = 0; i < 4; ++i)
#pragma unroll
            for (int j = 2; j < 4; ++j)
#pragma unroll
                for (int kq = 0; kq < 2; ++kq)
                    acc[i][j] = __builtin_amdgcn_mfma_f32_16x16x32_f16(
                        a[i][kq], b[j][kq], acc[i][j], 0, 0, 0);
        __builtin_amdgcn_s_setprio(0);
        BAR();

        // ---- P3: read A-high (8, reuses a[]); stage (t+2).Bh1; MFMA rows64-127 x cols0-31
#pragma unroll
        for (int i = 0; i < 4; ++i)
#pragma unroll
            for (int kq = 0; kq < 2; ++kq)
                a[i][kq] = *(const f16x8*)(smem + (aOff + dbuf
                                + (unsigned)(8192 + i * 2048 + kq * 64)));
        stage(sb + 2);
        BAR(); LGK0();
        __builtin_amdgcn_s_setprio(1);
#pragma unroll
        for (int i = 0; i < 4; ++i)
#pragma unroll
            for (int j = 0; j < 2; ++j)
#pragma unroll
                for (int kq = 0; kq < 2; ++kq)
                    acc[4 + i][j] = __builtin_amdgcn_mfma_f32_16x16x32_f16(
                        a[i][kq], b[j][kq], acc[4 + i][j], 0, 0, 0);
        __builtin_amdgcn_s_setprio(0);
        BAR();

        // ---- P4: stage (t+2).Ah0; counted vmcnt; MFMA rows64-127 x cols32-63
        stage(sb + 3);
        if (t < NT - 2) { asm volatile("s_waitcnt vmcnt(6)" ::: "memory"); }
        else            { asm volatile("s_waitcnt vmcnt(0)" ::: "memory"); }
        BAR();
        __builtin_amdgcn_s_setprio(1);
#pragma unroll
        for (int i = 0; i < 4; ++i)
#pragma unroll
            for (int j = 2; j < 4; ++j)
#pragma unroll
                for (int kq = 0; kq < 2; ++kq)
                    acc[4 + i][j] = __builtin_amdgcn_mfma_f32_16x16x32_f16(
                        a[i][kq], b[j][kq], acc[4 + i][j], 0, 0, 0);
        __builtin_amdgcn_s_setprio(0);
        BAR();
        __builtin_amdgcn_sched_barrier(0);
    }

    // ---- epilogue: out = acc*scale[n] + bdeq[n] ----
    const int rowBase = bm * 256 + wm * 128 + (l >> 4) * 4;
    const int colBase = bn * 256 + wn * 64 + (l & 15);
#pragma unroll
    for (int j = 0; j < 4; ++j) {
        const int n = colBase + j * 16;
        const float s = scale[n];
        const float bd = bdeq[n];
#pragma unroll
        for (int ri = 0; ri < 8; ++ri) {
            const int R = rowBase + (ri >> 2) * 64 + (ri & 3) * 16;
#pragma unroll
            for (int r = 0; r < 4; ++r)
                C[(size_t)(R + r) * N_DIM + n] = acc[ri][j][r] * s + bd;
        }
    }
}

// ---------------- fallback path (only if ws_size too small) ----------------
__global__ __launch_bounds__(256) void scale_only_kernel(
    const float* __restrict__ w, const float* __restrict__ bias,
    float* __restrict__ scale_out, float* __restrict__ bdeq_out)
{
    const int row = blockIdx.x;
    const int t = threadIdx.x;
    const float* wr = w + (size_t)row * K_DIM;
    float m = 0.f;
#pragma unroll
    for (int i = 0; i < 4; ++i) {
        float4 v = reinterpret_cast<const float4*>(wr)[i * 256 + t];
        m = fmaxf(m, fmaxf(fmaxf(fabsf(v.x), fabsf(v.y)),
                           fmaxf(fabsf(v.z), fabsf(v.w))));
    }
#pragma unroll
    for (int off = 32; off; off >>= 1)
        m = fmaxf(m, __shfl_xor(m, off, 64));
    __shared__ float wmax[4];
    if ((t & 63) == 0) wmax[t >> 6] = m;
    __syncthreads();
    if (t == 0) {
        float am = fmaxf(fmaxf(wmax[0], wmax[1]), fmaxf(wmax[2], wmax[3]));
        float scale = fmaxf(am, QSCALE_MIN) / QMAX;
        scale_out[row] = scale;
        bdeq_out[row]  = rintf(bias[row] / scale) * scale;
    }
}

__global__ __launch_bounds__(256) void fallback_gemm(
    const float* __restrict__ x, const float* __restrict__ w,
    const float* __restrict__ scale, const float* __restrict__ bdeq,
    float* __restrict__ C)
{
    __shared__ float xs[32][33];
    __shared__ float wt[32][33];
    const int nbn = N_DIM / 32;
    const int bn = blockIdx.x % nbn, bm = blockIdx.x / nbn;
    const int tx = threadIdx.x & 31, ty = threadIdx.x >> 5;
    float acc[4] = {0.f, 0.f, 0.f, 0.f};
    for (int kt = 0; kt < K_DIM; kt += 32) {
        __syncthreads();
#pragma unroll
        for (int i = 0; i < 4; ++i) {
            int r = ty + i * 8;
            xs[r][tx] = x[(size_t)(bm * 32 + r) * K_DIM + kt + tx];
            float s = scale[bn * 32 + r];
            float wv = w[(size_t)(bn * 32 + r) * K_DIM + kt + tx];
            wt[r][tx] = rintf(fminf(QMAX, fmaxf(-QMAX, wv / s))) * s;
        }
        __syncthreads();
#pragma unroll 8
        for (int kk = 0; kk < 32; ++kk) {
            float wv = wt[tx][kk];
#pragma unroll
            for (int i = 0; i < 4; ++i)
                acc[i] = fmaf(xs[ty + i * 8][kk], wv, acc[i]);
        }
    }
    const float bd = bdeq[bn * 32 + tx];
#pragma unroll
    for (int i = 0; i < 4; ++i)
        C[(size_t)(bm * 32 + ty + i * 8) * N_DIM + bn * 32 + tx] = acc[i] + bd;
}

extern "C" void kernel_launch(void* const* d_in, const int* in_sizes, int n_in,
                              void* d_out, int out_size, void* d_ws, size_t ws_size,
                              hipStream_t stream)
{
    const float* x    = (const float*)d_in[0];   // 4*2048*4096 f32
    const float* wgt  = (const float*)d_in[1];   // 4096*4096 f32
    const float* bias = (const float*)d_in[2];   // 4096 f32
    float* out = (float*)d_out;

    char* ws = (char*)d_ws;

    if (ws_size >= XH_BYTES + WH_BYTES + 2 * SCALE_BYTES) {
        _Float16* xh   = (_Float16*)(ws);
        _Float16* wh   = (_Float16*)(ws + XH_BYTES);
        float* scale   = (float*)(ws + XH_BYTES + WH_BYTES);
        float* bdeq    = scale + N_DIM;

        quant_weight_kernel<<<N_DIM, 256, 0, stream>>>(wgt, bias, wh, scale, bdeq);
        convert_x_kernel<<<4096, 256, 0, stream>>>(x, xh, (size_t)M_DIM * K_DIM / 8);
        gemm_kernel<<<(M_DIM / 256) * (N_DIM / 256), 512, 0, stream>>>(
            xh, wh, scale, bdeq, out);
    } else {
        float* scale = (float*)ws;
        float* bdeq  = scale + N_DIM;
        scale_only_kernel<<<N_DIM, 256, 0, stream>>>(wgt, bias, scale, bdeq);
        fallback_gemm<<<(M_DIM / 32) * (N_DIM / 32), 256, 0, stream>>>(
            x, wgt, scale, bdeq, out);
    }
}

// Round 9
// 483.525 us; speedup vs baseline: 1.1863x; 1.0654x over previous
//
#include <hip/hip_runtime.h>
#include <hip/hip_bf16.h>
#include <stdint.h>

typedef _Float16 f16x8 __attribute__((ext_vector_type(8)));
typedef _Float16 f16x4 __attribute__((ext_vector_type(4)));
typedef float    f32x4 __attribute__((ext_vector_type(4)));

#define QMAX 7.0f
#define QSCALE_MIN 2e-16f

#define M_DIM 8192
#define N_DIM 4096
#define K_DIM 4096

#define NT 64   // K tiles of BK=64

#define XH_BYTES ((size_t)M_DIM * K_DIM * 2)
#define WH_BYTES ((size_t)N_DIM * K_DIM * 2)
#define SCALE_BYTES ((size_t)N_DIM * 4)

typedef __attribute__((address_space(1))) const void gvoid;
typedef __attribute__((address_space(3))) void lvoid;

#define BAR()  asm volatile("s_barrier" ::: "memory")
#define LGK0() asm volatile("s_waitcnt lgkmcnt(0)" ::: "memory")

// ---------------- kernel 1: per-row weight quantize (one block per row) ----
__global__ __launch_bounds__(256) void quant_weight_kernel(
    const float* __restrict__ w, const float* __restrict__ bias,
    _Float16* __restrict__ wh, float* __restrict__ scale_out,
    float* __restrict__ bdeq_out)
{
    const int row = blockIdx.x;
    const int t = threadIdx.x;
    const float* wr = w + (size_t)row * K_DIM;

    float4 v[4];
#pragma unroll
    for (int i = 0; i < 4; ++i)
        v[i] = reinterpret_cast<const float4*>(wr)[i * 256 + t];

    float m = 0.f;
#pragma unroll
    for (int i = 0; i < 4; ++i) {
        m = fmaxf(m, fabsf(v[i].x));
        m = fmaxf(m, fabsf(v[i].y));
        m = fmaxf(m, fabsf(v[i].z));
        m = fmaxf(m, fabsf(v[i].w));
    }
#pragma unroll
    for (int off = 32; off; off >>= 1)
        m = fmaxf(m, __shfl_xor(m, off, 64));

    __shared__ float wmax[4];
    if ((t & 63) == 0) wmax[t >> 6] = m;
    __syncthreads();
    float am = fmaxf(fmaxf(wmax[0], wmax[1]), fmaxf(wmax[2], wmax[3]));
    float scale = fmaxf(am, QSCALE_MIN) / QMAX;

#pragma unroll
    for (int i = 0; i < 4; ++i) {
        float e[4] = { v[i].x, v[i].y, v[i].z, v[i].w };
        f16x4 q;
#pragma unroll
        for (int j = 0; j < 4; ++j) {
            float d = e[j] / scale;
            d = fminf(QMAX, fmaxf(-QMAX, d));
            q[j] = (_Float16)rintf(d);
        }
        reinterpret_cast<f16x4*>(wh + (size_t)row * K_DIM)[i * 256 + t] = q;
    }

    if (t == 0) {
        scale_out[row] = scale;
        bdeq_out[row]  = rintf(bias[row] / scale) * scale;
    }
}

// ---------------- kernel 2: x f32 -> f16 ----------------------------------
__global__ __launch_bounds__(256) void convert_x_kernel(
    const float* __restrict__ x, _Float16* __restrict__ xh, size_t n8)
{
    size_t i = (size_t)blockIdx.x * blockDim.x + threadIdx.x;
    size_t stride = (size_t)gridDim.x * blockDim.x;
    for (size_t c = i; c < n8; c += stride) {
        float4 a = reinterpret_cast<const float4*>(x)[c * 2];
        float4 b = reinterpret_cast<const float4*>(x)[c * 2 + 1];
        f16x8 h;
        h[0] = (_Float16)a.x; h[1] = (_Float16)a.y;
        h[2] = (_Float16)a.z; h[3] = (_Float16)a.w;
        h[4] = (_Float16)b.x; h[5] = (_Float16)b.y;
        h[6] = (_Float16)b.z; h[7] = (_Float16)b.w;
        reinterpret_cast<f16x8*>(xh)[c] = h;
    }
}

// ---------------- kernel 3: 256x256 8-phase GEMM, C = A*B^T ---------------
// A [M][K] f16, B [N][K] f16. 512 threads = 8 waves (2M x 4N), BK=64.
// LDS 128 KiB: A region [2 dbuf][2 half][128 rows][8 slots of 16B] at 0,
// B region at 65536. 3-bit slot swizzle: LDS[r][s] holds global[r][s^(r&7)],
// applied via pre-swizzled SOURCE lane permutation (linear gload_lds dest)
// + XOR'd ds_read slot (both-sides involution).
__global__ __launch_bounds__(512, 2) void gemm_kernel(
    const _Float16* __restrict__ A, const _Float16* __restrict__ B,
    const float* __restrict__ scale, const float* __restrict__ bdeq,
    float* __restrict__ C)
{
    __shared__ __attribute__((aligned(128))) char smem[131072];

    const int tid = threadIdx.x;
    const int l = tid & 63;
    const int w = tid >> 6;        // wave 0..7
    const int wm = w >> 2;         // 0..1  (rows wm*128..+128)
    const int wn = w & 3;          // 0..3  (cols wn*64..+64)

    // XCD bijective swizzle (512 blocks, 512%8==0)
    const int bid = blockIdx.x;
    const int swz = (bid & 7) * 64 + (bid >> 3);
    const int bm = swz >> 4;       // 0..31
    const int bn = swz & 15;       // 0..15

    // ---- read-side per-lane constants (3-bit slot swizzle folded in) ----
    const int lrow = l & 15;
    const unsigned slotbase = (unsigned)(((l >> 4) ^ (lrow & 7)) * 16);
    const unsigned aOff = (unsigned)(wm * 16384 + lrow * 128) + slotbase;
    const unsigned bOff = 65536u +
        (unsigned)((wn >> 1) * 16384 + (wn & 1) * 8192 + lrow * 128) + slotbase;

    // ---- stage-side lane permutation (inverse swizzle on global source) ----
    // LDS linear byte = tid*16 -> [row=tid>>3][slot=tid&7]; must hold
    // global[row][slot ^ (row&7)] -> source lane tp:
    const int tp = (tid & ~7) | ((tid ^ (tid >> 3)) & 7);
    const int rowq = tp >> 3;              // 0..63
    const int colE = (tp & 7) * 8;         // f16 elements
    const _Float16* aSrc = A + (size_t)(bm * 256 + rowq) * K_DIM + colE;
    const _Float16* bSrc = B + (size_t)(bn * 256 + rowq) * K_DIM + colE;
    const unsigned wOfs = (unsigned)(w * 1024);

    // half-tile issue sequence: s -> tile T=s>>2, part s&3: 0:Bh0 1:Bh1 2:Ah0 3:Ah1
    auto stage = [&](int s) {
        int T = s >> 2;
        if (T >= NT) return;
        int part = s & 3;
        int half = part & 1;
        bool isB = part < 2;
        const _Float16* src = (isB ? bSrc : aSrc)
                              + (size_t)(half * 128) * K_DIM + T * 64;
        unsigned dst = (isB ? 65536u : 0u) + (unsigned)((T & 1) * 32768)
                       + (unsigned)(half * 16384) + wOfs;
        __builtin_amdgcn_global_load_lds((gvoid*)src,
                                         (lvoid*)(smem + dst), 16, 0, 0);
        __builtin_amdgcn_global_load_lds((gvoid*)(src + (size_t)64 * K_DIM),
                                         (lvoid*)(smem + dst + 8192), 16, 0, 0);
    };

    f32x4 acc[8][4];
#pragma unroll
    for (int i = 0; i < 8; ++i)
#pragma unroll
        for (int j = 0; j < 4; ++j)
            acc[i][j] = (f32x4){0.f, 0.f, 0.f, 0.f};

    f16x8 a[4][2], b[4][2];

    // ---- prologue: tile0 complete + tile1 first 3 halves ----
    stage(0); stage(1); stage(2); stage(3);
    asm volatile("s_waitcnt vmcnt(4)" ::: "memory");
    stage(4); stage(5); stage(6);
    asm volatile("s_waitcnt vmcnt(6)" ::: "memory");
    BAR();

    for (int t = 0; t < NT; ++t) {
        const unsigned dbuf = (unsigned)((t & 1) * 32768);
        const int sb = 7 + 4 * t;

        // ---- P1: read A-low + all B; stage (t+1).Ah1; MFMA rows0-63 x cols0-31
#pragma unroll
        for (int i = 0; i < 4; ++i)
#pragma unroll
            for (int kq = 0; kq < 2; ++kq)
                a[i][kq] = *(const f16x8*)(smem +
                    ((aOff + dbuf + (unsigned)(i * 2048)) ^ (unsigned)(kq * 64)));
#pragma unroll
        for (int j = 0; j < 4; ++j)
#pragma unroll
            for (int kq = 0; kq < 2; ++kq)
                b[j][kq] = *(const f16x8*)(smem +
                    ((bOff + dbuf + (unsigned)(j * 2048)) ^ (unsigned)(kq * 64)));
        stage(sb);
        BAR(); LGK0();
        __builtin_amdgcn_s_setprio(1);
#pragma unroll
        for (int i = 0; i < 4; ++i)
#pragma unroll
            for (int j = 0; j < 2; ++j)
#pragma unroll
                for (int kq = 0; kq < 2; ++kq)
                    acc[i][j] = __builtin_amdgcn_mfma_f32_16x16x32_f16(
                        a[i][kq], b[j][kq], acc[i][j], 0, 0, 0);
        __builtin_amdgcn_s_setprio(0);
        BAR();

        // ---- P2: stage (t+2).Bh0; MFMA rows0-63 x cols32-63
        stage(sb + 1);
        BAR(); LGK0();
        __builtin_amdgcn_s_setprio(1);
#pragma unroll
        for (int i = 0; i < 4; ++i)
#pragma unroll
            for (int j = 2; j < 4; ++j)
#pragma unroll
                for (int kq = 0; kq < 2; ++kq)
                    acc[i][j] = __builtin_amdgcn_mfma_f32_16x16x32_f16(
                        a[i][kq], b[j][kq], acc[i][j], 0, 0, 0);
        __builtin_amdgcn_s_setprio(0);
        BAR();

        // ---- P3: read A-high; stage (t+2).Bh1; MFMA rows64-127 x cols0-31
#pragma unroll
        for (int i = 0; i < 4; ++i)
#pragma unroll
            for (int kq = 0; kq < 2; ++kq)
                a[i][kq] = *(const f16x8*)(smem +
                    ((aOff + dbuf + (unsigned)(8192 + i * 2048)) ^ (unsigned)(kq * 64)));
        stage(sb + 2);
        BAR(); LGK0();
        __builtin_amdgcn_s_setprio(1);
#pragma unroll
        for (int i = 0; i < 4; ++i)
#pragma unroll
            for (int j = 0; j < 2; ++j)
#pragma unroll
                for (int kq = 0; kq < 2; ++kq)
                    acc[4 + i][j] = __builtin_amdgcn_mfma_f32_16x16x32_f16(
                        a[i][kq], b[j][kq], acc[4 + i][j], 0, 0, 0);
        __builtin_amdgcn_s_setprio(0);
        BAR();

        // ---- P4: stage (t+2).Ah0; counted vmcnt; MFMA rows64-127 x cols32-63
        stage(sb + 3);
        if (t < NT - 2) { asm volatile("s_waitcnt vmcnt(6)" ::: "memory"); }
        else            { asm volatile("s_waitcnt vmcnt(0)" ::: "memory"); }
        BAR();
        __builtin_amdgcn_s_setprio(1);
#pragma unroll
        for (int i = 0; i < 4; ++i)
#pragma unroll
            for (int j = 2; j < 4; ++j)
#pragma unroll
                for (int kq = 0; kq < 2; ++kq)
                    acc[4 + i][j] = __builtin_amdgcn_mfma_f32_16x16x32_f16(
                        a[i][kq], b[j][kq], acc[4 + i][j], 0, 0, 0);
        __builtin_amdgcn_s_setprio(0);
        BAR();
        __builtin_amdgcn_sched_barrier(0);
    }

    // ---- epilogue: out = acc*scale[n] + bdeq[n] ----
    const int rowBase = bm * 256 + wm * 128 + (l >> 4) * 4;
    const int colBase = bn * 256 + wn * 64 + (l & 15);
#pragma unroll
    for (int j = 0; j < 4; ++j) {
        const int n = colBase + j * 16;
        const float s = scale[n];
        const float bd = bdeq[n];
#pragma unroll
        for (int ri = 0; ri < 8; ++ri) {
            const int R = rowBase + (ri >> 2) * 64 + (ri & 3) * 16;
#pragma unroll
            for (int r = 0; r < 4; ++r)
                C[(size_t)(R + r) * N_DIM + n] = acc[ri][j][r] * s + bd;
        }
    }
}

// ---------------- fallback path (only if ws_size too small) ----------------
__global__ __launch_bounds__(256) void scale_only_kernel(
    const float* __restrict__ w, const float* __restrict__ bias,
    float* __restrict__ scale_out, float* __restrict__ bdeq_out)
{
    const int row = blockIdx.x;
    const int t = threadIdx.x;
    const float* wr = w + (size_t)row * K_DIM;
    float m = 0.f;
#pragma unroll
    for (int i = 0; i < 4; ++i) {
        float4 v = reinterpret_cast<const float4*>(wr)[i * 256 + t];
        m = fmaxf(m, fmaxf(fmaxf(fabsf(v.x), fabsf(v.y)),
                           fmaxf(fabsf(v.z), fabsf(v.w))));
    }
#pragma unroll
    for (int off = 32; off; off >>= 1)
        m = fmaxf(m, __shfl_xor(m, off, 64));
    __shared__ float wmax[4];
    if ((t & 63) == 0) wmax[t >> 6] = m;
    __syncthreads();
    if (t == 0) {
        float am = fmaxf(fmaxf(wmax[0], wmax[1]), fmaxf(wmax[2], wmax[3]));
        float scale = fmaxf(am, QSCALE_MIN) / QMAX;
        scale_out[row] = scale;
        bdeq_out[row]  = rintf(bias[row] / scale) * scale;
    }
}

__global__ __launch_bounds__(256) void fallback_gemm(
    const float* __restrict__ x, const float* __restrict__ w,
    const float* __restrict__ scale, const float* __restrict__ bdeq,
    float* __restrict__ C)
{
    __shared__ float xs[32][33];
    __shared__ float wt[32][33];
    const int nbn = N_DIM / 32;
    const int bn = blockIdx.x % nbn, bm = blockIdx.x / nbn;
    const int tx = threadIdx.x & 31, ty = threadIdx.x >> 5;
    float acc[4] = {0.f, 0.f, 0.f, 0.f};
    for (int kt = 0; kt < K_DIM; kt += 32) {
        __syncthreads();
#pragma unroll
        for (int i = 0; i < 4; ++i) {
            int r = ty + i * 8;
            xs[r][tx] = x[(size_t)(bm * 32 + r) * K_DIM + kt + tx];
            float s = scale[bn * 32 + r];
            float wv = w[(size_t)(bn * 32 + r) * K_DIM + kt + tx];
            wt[r][tx] = rintf(fminf(QMAX, fmaxf(-QMAX, wv / s))) * s;
        }
        __syncthreads();
#pragma unroll 8
        for (int kk = 0; kk < 32; ++kk) {
            float wv = wt[tx][kk];
#pragma unroll
            for (int i = 0; i < 4; ++i)
                acc[i] = fmaf(xs[ty + i * 8][kk], wv, acc[i]);
        }
    }
    const float bd = bdeq[bn * 32 + tx];
#pragma unroll
    for (int i = 0; i < 4; ++i)
        C[(size_t)(bm * 32 + ty + i * 8) * N_DIM + bn * 32 + tx] = acc[i] + bd;
}

extern "C" void kernel_launch(void* const* d_in, const int* in_sizes, int n_in,
                              void* d_out, int out_size, void* d_ws, size_t ws_size,
                              hipStream_t stream)
{
    const float* x    = (const float*)d_in[0];   // 4*2048*4096 f32
    const float* wgt  = (const float*)d_in[1];   // 4096*4096 f32
    const float* bias = (const float*)d_in[2];   // 4096 f32
    float* out = (float*)d_out;

    char* ws = (char*)d_ws;

    if (ws_size >= XH_BYTES + WH_BYTES + 2 * SCALE_BYTES) {
        _Float16* xh   = (_Float16*)(ws);
        _Float16* wh   = (_Float16*)(ws + XH_BYTES);
        float* scale   = (float*)(ws + XH_BYTES + WH_BYTES);
        float* bdeq    = scale + N_DIM;

        quant_weight_kernel<<<N_DIM, 256, 0, stream>>>(wgt, bias, wh, scale, bdeq);
        convert_x_kernel<<<4096, 256, 0, stream>>>(x, xh, (size_t)M_DIM * K_DIM / 8);
        gemm_kernel<<<(M_DIM / 256) * (N_DIM / 256), 512, 0, stream>>>(
            xh, wh, scale, bdeq, out);
    } else {
        float* scale = (float*)ws;
        float* bdeq  = scale + N_DIM;
        scale_only_kernel<<<N_DIM, 256, 0, stream>>>(wgt, bias, scale, bdeq);
        fallback_gemm<<<(M_DIM / 32) * (N_DIM / 32), 256, 0, stream>>>(
            x, wgt, scale, bdeq, out);
    }
}

// Round 10
// 480.099 us; speedup vs baseline: 1.1948x; 1.0071x over previous
//
#include <hip/hip_runtime.h>
#include <hip/hip_bf16.h>
#include <stdint.h>

typedef _Float16 f16x8 __attribute__((ext_vector_type(8)));
typedef _Float16 f16x4 __attribute__((ext_vector_type(4)));
typedef float    f32x4 __attribute__((ext_vector_type(4)));

#define QMAX 7.0f
#define QSCALE_MIN 2e-16f

#define M_DIM 8192
#define N_DIM 4096
#define K_DIM 4096

#define NT 64   // K tiles of BK=64

#define XH_BYTES ((size_t)M_DIM * K_DIM * 2)
#define WH_BYTES ((size_t)N_DIM * K_DIM * 2)
#define SCALE_BYTES ((size_t)N_DIM * 4)

typedef __attribute__((address_space(1))) const void gvoid;
typedef __attribute__((address_space(3))) void lvoid;

#define BAR()  asm volatile("s_barrier" ::: "memory")
#define LGK0() asm volatile("s_waitcnt lgkmcnt(0)" ::: "memory")

// ---------------- kernel 1: per-row weight quantize (one block per row) ----
__global__ __launch_bounds__(256) void quant_weight_kernel(
    const float* __restrict__ w, const float* __restrict__ bias,
    _Float16* __restrict__ wh, float* __restrict__ scale_out,
    float* __restrict__ bdeq_out)
{
    const int row = blockIdx.x;
    const int t = threadIdx.x;
    const float* wr = w + (size_t)row * K_DIM;

    float4 v[4];
#pragma unroll
    for (int i = 0; i < 4; ++i)
        v[i] = reinterpret_cast<const float4*>(wr)[i * 256 + t];

    float m = 0.f;
#pragma unroll
    for (int i = 0; i < 4; ++i) {
        m = fmaxf(m, fabsf(v[i].x));
        m = fmaxf(m, fabsf(v[i].y));
        m = fmaxf(m, fabsf(v[i].z));
        m = fmaxf(m, fabsf(v[i].w));
    }
#pragma unroll
    for (int off = 32; off; off >>= 1)
        m = fmaxf(m, __shfl_xor(m, off, 64));

    __shared__ float wmax[4];
    if ((t & 63) == 0) wmax[t >> 6] = m;
    __syncthreads();
    float am = fmaxf(fmaxf(wmax[0], wmax[1]), fmaxf(wmax[2], wmax[3]));
    float scale = fmaxf(am, QSCALE_MIN) / QMAX;

#pragma unroll
    for (int i = 0; i < 4; ++i) {
        float e[4] = { v[i].x, v[i].y, v[i].z, v[i].w };
        f16x4 q;
#pragma unroll
        for (int j = 0; j < 4; ++j) {
            float d = e[j] / scale;
            d = fminf(QMAX, fmaxf(-QMAX, d));
            q[j] = (_Float16)rintf(d);
        }
        reinterpret_cast<f16x4*>(wh + (size_t)row * K_DIM)[i * 256 + t] = q;
    }

    if (t == 0) {
        scale_out[row] = scale;
        bdeq_out[row]  = rintf(bias[row] / scale) * scale;
    }
}

// ---------------- kernel 2: x f32 -> f16 ----------------------------------
__global__ __launch_bounds__(256) void convert_x_kernel(
    const float* __restrict__ x, _Float16* __restrict__ xh, size_t n8)
{
    size_t i = (size_t)blockIdx.x * blockDim.x + threadIdx.x;
    size_t stride = (size_t)gridDim.x * blockDim.x;
    for (size_t c = i; c < n8; c += stride) {
        float4 a = reinterpret_cast<const float4*>(x)[c * 2];
        float4 b = reinterpret_cast<const float4*>(x)[c * 2 + 1];
        f16x8 h;
        h[0] = (_Float16)a.x; h[1] = (_Float16)a.y;
        h[2] = (_Float16)a.z; h[3] = (_Float16)a.w;
        h[4] = (_Float16)b.x; h[5] = (_Float16)b.y;
        h[6] = (_Float16)b.z; h[7] = (_Float16)b.w;
        reinterpret_cast<f16x8*>(xh)[c] = h;
    }
}

// ---------------- kernel 3: 256x256 8-phase GEMM, C = A*B^T ---------------
// A [M][K] f16, B [N][K] f16. 512 threads = 8 waves (2M x 4N), BK=64.
// LDS 128 KiB: A [2 dbuf][2 half][128 rows][8 slots of 16B] at 0, B at 65536.
// 3-bit slot swizzle (conflicts measured 0): LDS[r][s] = global[r][s^(r&7)],
// pre-swizzled SOURCE lane perm + XOR'd ds_read slot.
// Read distribution 8/4/8/4 across phases (round-9 fix: was 16/0/8/0 with
// P1's all-wave 128-instr LDS burst fully exposed between barriers).
__global__ __launch_bounds__(512, 2) void gemm_kernel(
    const _Float16* __restrict__ A, const _Float16* __restrict__ B,
    const float* __restrict__ scale, const float* __restrict__ bdeq,
    float* __restrict__ C)
{
    __shared__ __attribute__((aligned(128))) char smem[131072];

    const int tid = threadIdx.x;
    const int l = tid & 63;
    const int w = tid >> 6;        // wave 0..7
    const int wm = w >> 2;         // 0..1  (rows wm*128..+128)
    const int wn = w & 3;          // 0..3  (cols wn*64..+64)

    // XCD bijective swizzle (512 blocks, 512%8==0)
    const int bid = blockIdx.x;
    const int swz = (bid & 7) * 64 + (bid >> 3);
    const int bm = swz >> 4;       // 0..31
    const int bn = swz & 15;       // 0..15

    // ---- read-side per-lane constants (3-bit slot swizzle folded in) ----
    const int lrow = l & 15;
    const unsigned slotbase = (unsigned)(((l >> 4) ^ (lrow & 7)) * 16);
    const unsigned aOff = (unsigned)(wm * 16384 + lrow * 128) + slotbase;
    const unsigned bOff = 65536u +
        (unsigned)((wn >> 1) * 16384 + (wn & 1) * 8192 + lrow * 128) + slotbase;

    // ---- stage-side lane permutation (inverse swizzle on global source) ----
    const int tp = (tid & ~7) | ((tid ^ (tid >> 3)) & 7);
    const int rowq = tp >> 3;              // 0..63
    const int colE = (tp & 7) * 8;         // f16 elements
    const _Float16* aSrc = A + (size_t)(bm * 256 + rowq) * K_DIM + colE;
    const _Float16* bSrc = B + (size_t)(bn * 256 + rowq) * K_DIM + colE;
    const unsigned wOfs = (unsigned)(w * 1024);

    // half-tile issue sequence: s -> tile T=s>>2, part s&3: 0:Bh0 1:Bh1 2:Ah0 3:Ah1
    auto stage = [&](int s) {
        int T = s >> 2;
        if (T >= NT) return;
        int part = s & 3;
        int half = part & 1;
        bool isB = part < 2;
        const _Float16* src = (isB ? bSrc : aSrc)
                              + (size_t)(half * 128) * K_DIM + T * 64;
        unsigned dst = (isB ? 65536u : 0u) + (unsigned)((T & 1) * 32768)
                       + (unsigned)(half * 16384) + wOfs;
        __builtin_amdgcn_global_load_lds((gvoid*)src,
                                         (lvoid*)(smem + dst), 16, 0, 0);
        __builtin_amdgcn_global_load_lds((gvoid*)(src + (size_t)64 * K_DIM),
                                         (lvoid*)(smem + dst + 8192), 16, 0, 0);
    };

    f32x4 acc[8][4];
#pragma unroll
    for (int i = 0; i < 8; ++i)
#pragma unroll
        for (int j = 0; j < 4; ++j)
            acc[i][j] = (f32x4){0.f, 0.f, 0.f, 0.f};

    f16x8 a[4][2], b[4][2];

    // ---- prologue: tile0 complete + tile1 first 3 halves ----
    stage(0); stage(1); stage(2); stage(3);
    asm volatile("s_waitcnt vmcnt(4)" ::: "memory");
    stage(4); stage(5); stage(6);
    asm volatile("s_waitcnt vmcnt(6)" ::: "memory");
    BAR();

    // pre-load tile0's B-left (cols 0-31 of this wave) into b[0..1]
#pragma unroll
    for (int j = 0; j < 2; ++j)
#pragma unroll
        for (int kq = 0; kq < 2; ++kq)
            b[j][kq] = *(const f16x8*)(smem +
                ((bOff + (unsigned)(j * 2048)) ^ (unsigned)(kq * 64)));

    for (int t = 0; t < NT; ++t) {
        const unsigned dbuf = (unsigned)((t & 1) * 32768);
        const int sb = 7 + 4 * t;

        // ---- P1: read A-low (8); stage (t+1).Ah1; MFMA rows0-63 x cols0-31
#pragma unroll
        for (int i = 0; i < 4; ++i)
#pragma unroll
            for (int kq = 0; kq < 2; ++kq)
                a[i][kq] = *(const f16x8*)(smem +
                    ((aOff + dbuf + (unsigned)(i * 2048)) ^ (unsigned)(kq * 64)));
        stage(sb);
        BAR(); LGK0();
        __builtin_amdgcn_s_setprio(1);
#pragma unroll
        for (int i = 0; i < 4; ++i)
#pragma unroll
            for (int j = 0; j < 2; ++j)
#pragma unroll
                for (int kq = 0; kq < 2; ++kq)
                    acc[i][j] = __builtin_amdgcn_mfma_f32_16x16x32_f16(
                        a[i][kq], b[j][kq], acc[i][j], 0, 0, 0);
        __builtin_amdgcn_s_setprio(0);
        BAR();

        // ---- P2: read B-right (4) into b[2..3]; LGK0 (read completes before
        //          same-region (t+2).Bh0 stage can land); stage; MFMA cols32-63
#pragma unroll
        for (int j = 2; j < 4; ++j)
#pragma unroll
            for (int kq = 0; kq < 2; ++kq)
                b[j][kq] = *(const f16x8*)(smem +
                    ((bOff + dbuf + (unsigned)(j * 2048)) ^ (unsigned)(kq * 64)));
        LGK0();
        stage(sb + 1);
        BAR();
        __builtin_amdgcn_s_setprio(1);
#pragma unroll
        for (int i = 0; i < 4; ++i)
#pragma unroll
            for (int j = 2; j < 4; ++j)
#pragma unroll
                for (int kq = 0; kq < 2; ++kq)
                    acc[i][j] = __builtin_amdgcn_mfma_f32_16x16x32_f16(
                        a[i][kq], b[j][kq], acc[i][j], 0, 0, 0);
        __builtin_amdgcn_s_setprio(0);
        BAR();

        // ---- P3: read A-high (8); stage (t+2).Bh1; MFMA rows64-127 x cols0-31
#pragma unroll
        for (int i = 0; i < 4; ++i)
#pragma unroll
            for (int kq = 0; kq < 2; ++kq)
                a[i][kq] = *(const f16x8*)(smem +
                    ((aOff + dbuf + (unsigned)(8192 + i * 2048)) ^ (unsigned)(kq * 64)));
        stage(sb + 2);
        BAR(); LGK0();
        __builtin_amdgcn_s_setprio(1);
#pragma unroll
        for (int i = 0; i < 4; ++i)
#pragma unroll
            for (int j = 0; j < 2; ++j)
#pragma unroll
                for (int kq = 0; kq < 2; ++kq)
                    acc[4 + i][j] = __builtin_amdgcn_mfma_f32_16x16x32_f16(
                        a[i][kq], b[j][kq], acc[4 + i][j], 0, 0, 0);
        __builtin_amdgcn_s_setprio(0);
        BAR();

        // ---- P4: stage (t+2).Ah0; counted vmcnt; prefetch (t+1).B-left into
        //          b[0..1] (dead after P3; t+1 landed per vmcnt); MFMA cols32-63
        stage(sb + 3);
        if (t < NT - 2) { asm volatile("s_waitcnt vmcnt(6)" ::: "memory"); }
        else            { asm volatile("s_waitcnt vmcnt(0)" ::: "memory"); }
        BAR();
        if (t < NT - 1) {
            const unsigned dbufN = (unsigned)(((t + 1) & 1) * 32768);
#pragma unroll
            for (int j = 0; j < 2; ++j)
#pragma unroll
                for (int kq = 0; kq < 2; ++kq)
                    b[j][kq] = *(const f16x8*)(smem +
                        ((bOff + dbufN + (unsigned)(j * 2048)) ^ (unsigned)(kq * 64)));
        }
        __builtin_amdgcn_s_setprio(1);
#pragma unroll
        for (int i = 0; i < 4; ++i)
#pragma unroll
            for (int j = 2; j < 4; ++j)
#pragma unroll
                for (int kq = 0; kq < 2; ++kq)
                    acc[4 + i][j] = __builtin_amdgcn_mfma_f32_16x16x32_f16(
                        a[i][kq], b[j][kq], acc[4 + i][j], 0, 0, 0);
        __builtin_amdgcn_s_setprio(0);
        BAR();
        __builtin_amdgcn_sched_barrier(0);
    }

    // ---- epilogue: out = acc*scale[n] + bdeq[n] ----
    const int rowBase = bm * 256 + wm * 128 + (l >> 4) * 4;
    const int colBase = bn * 256 + wn * 64 + (l & 15);
#pragma unroll
    for (int j = 0; j < 4; ++j) {
        const int n = colBase + j * 16;
        const float s = scale[n];
        const float bd = bdeq[n];
#pragma unroll
        for (int ri = 0; ri < 8; ++ri) {
            const int R = rowBase + (ri >> 2) * 64 + (ri & 3) * 16;
#pragma unroll
            for (int r = 0; r < 4; ++r)
                C[(size_t)(R + r) * N_DIM + n] = acc[ri][j][r] * s + bd;
        }
    }
}

// ---------------- fallback path (only if ws_size too small) ----------------
__global__ __launch_bounds__(256) void scale_only_kernel(
    const float* __restrict__ w, const float* __restrict__ bias,
    float* __restrict__ scale_out, float* __restrict__ bdeq_out)
{
    const int row = blockIdx.x;
    const int t = threadIdx.x;
    const float* wr = w + (size_t)row * K_DIM;
    float m = 0.f;
#pragma unroll
    for (int i = 0; i < 4; ++i) {
        float4 v = reinterpret_cast<const float4*>(wr)[i * 256 + t];
        m = fmaxf(m, fmaxf(fmaxf(fabsf(v.x), fabsf(v.y)),
                           fmaxf(fabsf(v.z), fabsf(v.w))));
    }
#pragma unroll
    for (int off = 32; off; off >>= 1)
        m = fmaxf(m, __shfl_xor(m, off, 64));
    __shared__ float wmax[4];
    if ((t & 63) == 0) wmax[t >> 6] = m;
    __syncthreads();
    if (t == 0) {
        float am = fmaxf(fmaxf(wmax[0], wmax[1]), fmaxf(wmax[2], wmax[3]));
        float scale = fmaxf(am, QSCALE_MIN) / QMAX;
        scale_out[row] = scale;
        bdeq_out[row]  = rintf(bias[row] / scale) * scale;
    }
}

__global__ __launch_bounds__(256) void fallback_gemm(
    const float* __restrict__ x, const float* __restrict__ w,
    const float* __restrict__ scale, const float* __restrict__ bdeq,
    float* __restrict__ C)
{
    __shared__ float xs[32][33];
    __shared__ float wt[32][33];
    const int nbn = N_DIM / 32;
    const int bn = blockIdx.x % nbn, bm = blockIdx.x / nbn;
    const int tx = threadIdx.x & 31, ty = threadIdx.x >> 5;
    float acc[4] = {0.f, 0.f, 0.f, 0.f};
    for (int kt = 0; kt < K_DIM; kt += 32) {
        __syncthreads();
#pragma unroll
        for (int i = 0; i < 4; ++i) {
            int r = ty + i * 8;
            xs[r][tx] = x[(size_t)(bm * 32 + r) * K_DIM + kt + tx];
            float s = scale[bn * 32 + r];
            float wv = w[(size_t)(bn * 32 + r) * K_DIM + kt + tx];
            wt[r][tx] = rintf(fminf(QMAX, fmaxf(-QMAX, wv / s))) * s;
        }
        __syncthreads();
#pragma unroll 8
        for (int kk = 0; kk < 32; ++kk) {
            float wv = wt[tx][kk];
#pragma unroll
            for (int i = 0; i < 4; ++i)
                acc[i] = fmaf(xs[ty + i * 8][kk], wv, acc[i]);
        }
    }
    const float bd = bdeq[bn * 32 + tx];
#pragma unroll
    for (int i = 0; i < 4; ++i)
        C[(size_t)(bm * 32 + ty + i * 8) * N_DIM + bn * 32 + tx] = acc[i] + bd;
}

extern "C" void kernel_launch(void* const* d_in, const int* in_sizes, int n_in,
                              void* d_out, int out_size, void* d_ws, size_t ws_size,
                              hipStream_t stream)
{
    const float* x    = (const float*)d_in[0];   // 4*2048*4096 f32
    const float* wgt  = (const float*)d_in[1];   // 4096*4096 f32
    const float* bias = (const float*)d_in[2];   // 4096 f32
    float* out = (float*)d_out;

    char* ws = (char*)d_ws;

    if (ws_size >= XH_BYTES + WH_BYTES + 2 * SCALE_BYTES) {
        _Float16* xh   = (_Float16*)(ws);
        _Float16* wh   = (_Float16*)(ws + XH_BYTES);
        float* scale   = (float*)(ws + XH_BYTES + WH_BYTES);
        float* bdeq    = scale + N_DIM;

        quant_weight_kernel<<<N_DIM, 256, 0, stream>>>(wgt, bias, wh, scale, bdeq);
        convert_x_kernel<<<4096, 256, 0, stream>>>(x, xh, (size_t)M_DIM * K_DIM / 8);
        gemm_kernel<<<(M_DIM / 256) * (N_DIM / 256), 512, 0, stream>>>(
            xh, wh, scale, bdeq, out);
    } else {
        float* scale = (float*)ws;
        float* bdeq  = scale + N_DIM;
        scale_only_kernel<<<N_DIM, 256, 0, stream>>>(wgt, bias, scale, bdeq);
        fallback_gemm<<<(M_DIM / 32) * (N_DIM / 32), 256, 0, stream>>>(
            x, wgt, scale, bdeq, out);
    }
}